// Round 8
// baseline (42.847 us; speedup 1.0000x reference)
//
#include <hip/hip_runtime.h>
#include <hip/hip_bf16.h>

// CP tensorized embedding gather — TWO-KERNEL split:
//   A) cpemb_w:      w[t,r] = bf16( U0[a,r]*U1[b,r]*U2[c,r] )  -> d_ws (13 MB)
//   B) cpemb_expand: out[t,e] = sum_r w[t,r] * B[r,e],  B[r,e]=V0[e>>4,r]*V1[e&15,r]
// Rationale (r2..r7 evidence): store geometry is NOT the limiter (scalar /
// dwordx4 / LDS-staged contiguous all ~3.8 TB/s); the per-tile serial front-end
// (x -> decode -> 6 divergent gathers -> cvt) is. Kernel B has no gathers:
// one coalesced 16B/lane load of w per tile (already in MFMA A-frag order),
// 8 MFMAs, 8 wide stores; all tile-loads hoisted before any store so no
// vmcnt FIFO entanglement. w is L2/L3-resident between kernels.

#define RANKK 32
#define EMB 128
#define TPW 4   // tiles per wave in kernel B

typedef __attribute__((ext_vector_type(8))) short short8v;  // 8 bf16 = 4 VGPRs
typedef __attribute__((ext_vector_type(4))) float f32x4;

__device__ __forceinline__ short f2bf(float f) {
    union { __hip_bfloat16 h; short s; } u;
    u.h = __float2bfloat16(f);   // RNE
    return u.s;
}

// ---------------- kernel A: token weights -> d_ws ----------------
// wave = 16 tokens; lane (t_l, g) computes w[tok][g*8 .. g*8+7] and stores
// 16 B; per-wave store span = 1 KB contiguous.
__global__ __launch_bounds__(256) void cpemb_w(
    const int* __restrict__ x,
    const float* __restrict__ U0, const float* __restrict__ U1,
    const float* __restrict__ U2,
    short* __restrict__ w, int ntok)
{
    const int tid  = threadIdx.x;
    const int lane = tid & 63;
    const int base = blockIdx.x * 64 + (tid >> 6) * 16;   // 64 tokens/block
    const int t_l  = lane & 15;
    const int g    = lane >> 4;
    const int rb   = g * 8;

    int tok = base + t_l;
    const bool ok = tok < ntok;
    if (!ok) tok = ntok - 1;

    const unsigned ui  = (unsigned)x[tok];
    const unsigned a   = ui / 5000u;
    const unsigned rem = ui - a * 5000u;
    const unsigned b   = rem / 50u;
    const unsigned c   = rem - b * 50u;

    const float4* p0 = (const float4*)(U0 + a * RANKK + rb);
    const float4* p1 = (const float4*)(U1 + b * RANKK + rb);
    const float4* p2 = (const float4*)(U2 + c * RANKK + rb);
    float4 a0 = p0[0], a1 = p0[1];
    float4 b0 = p1[0], b1 = p1[1];
    float4 c0 = p2[0], c1 = p2[1];

    float wv[8];
    wv[0]=a0.x*b0.x*c0.x; wv[1]=a0.y*b0.y*c0.y;
    wv[2]=a0.z*b0.z*c0.z; wv[3]=a0.w*b0.w*c0.w;
    wv[4]=a1.x*b1.x*c1.x; wv[5]=a1.y*b1.y*c1.y;
    wv[6]=a1.z*b1.z*c1.z; wv[7]=a1.w*b1.w*c1.w;

    short8v sv;
    #pragma unroll
    for (int i = 0; i < 8; ++i) sv[i] = f2bf(wv[i]);

    if (ok)
        *(short8v*)(w + (size_t)tok * RANKK + rb) = sv;
}

// ---------------- kernel B: expand w -> out ----------------
// wave owns TPW consecutive 16-token tiles (32 KB contiguous output).
// All TPW afrag loads issued up front; then per tile: 8 MFMA + 8 dwordx4.
__global__ __launch_bounds__(256) void cpemb_expand(
    const short* __restrict__ w,
    const float* __restrict__ V0, const float* __restrict__ V1,
    float* __restrict__ out, int ntok)
{
    const int tid  = threadIdx.x;
    const int lane = tid & 63;
    const int gw   = blockIdx.x * 4 + (tid >> 6);   // wave id
    const int t_l  = lane & 15;
    const int g    = lane >> 4;
    const int rb   = g * 8;

    const int grp0    = gw * TPW;
    const int ngroups = (ntok + 15) >> 4;
    if (grp0 >= ngroups) return;

    // ---- hoisted afrag loads (independent, before any store exists)
    short8v af[TPW];
    #pragma unroll
    for (int k = 0; k < TPW; ++k) {
        int grp = grp0 + k;
        if (grp >= ngroups) grp = ngroups - 1;
        af[k] = *(const short8v*)(w + ((size_t)(grp * 16 + t_l)) * RANKK + rb);
    }

    // ---- table fragments (MFMA A operand; transposed-D):
    // A[m=e_in_block][k]: lane's m = t_l -> V1 row = t_l; V0 row = eb.
    float v1r[8];
    {
        const float4* p = (const float4*)(V1 + t_l * RANKK + rb);
        float4 lo = p[0], hi = p[1];
        v1r[0]=lo.x; v1r[1]=lo.y; v1r[2]=lo.z; v1r[3]=lo.w;
        v1r[4]=hi.x; v1r[5]=hi.y; v1r[6]=hi.z; v1r[7]=hi.w;
    }
    short8v bfrag[8];
    #pragma unroll
    for (int eb = 0; eb < 8; ++eb) {
        const float4* p = (const float4*)(V0 + eb * RANKK + rb);
        float4 lo = p[0], hi = p[1];
        float v0r[8] = {lo.x, lo.y, lo.z, lo.w, hi.x, hi.y, hi.z, hi.w};
        #pragma unroll
        for (int i = 0; i < 8; ++i)
            bfrag[eb][i] = f2bf(v0r[i] * v1r[i]);
    }

    // ---- per tile: 8 MFMAs (transposed D) + 8 wide stores
    #pragma unroll
    for (int k = 0; k < TPW; ++k) {
        const int grp = grp0 + k;
        if (grp >= ngroups) break;
        const int t0 = grp << 4;
        const bool ok = (t0 + t_l) < ntok;
        float* orow = out + (size_t)(t0 + t_l) * EMB + g * 4;
        #pragma unroll
        for (int eb = 0; eb < 8; ++eb) {
            f32x4 z = {0.f, 0.f, 0.f, 0.f};
            f32x4 acc = __builtin_amdgcn_mfma_f32_16x16x32_bf16(bfrag[eb], af[k], z, 0, 0, 0);
            if (ok) {
                float4 v = make_float4(acc[0], acc[1], acc[2], acc[3]);
                *(float4*)(orow + eb * 16) = v;   // token row, e = eb*16+g*4..+3
            }
        }
    }
}

extern "C" void kernel_launch(void* const* d_in, const int* in_sizes, int n_in,
                              void* d_out, int out_size, void* d_ws, size_t ws_size,
                              hipStream_t stream) {
    const int*   x  = (const int*)d_in[0];
    const float* U0 = (const float*)d_in[1];
    const float* U1 = (const float*)d_in[2];
    const float* U2 = (const float*)d_in[3];
    const float* V0 = (const float*)d_in[4];
    const float* V1 = (const float*)d_in[5];
    float* out = (float*)d_out;
    short* w   = (short*)d_ws;                  // ntok*32 bf16 = 13.1 MB

    const int ntok = in_sizes[0];               // 204800
    const int ngroups = (ntok + 15) >> 4;       // 12800 tiles

    // A: 64 tokens/block
    const int blocksA = (ntok + 63) >> 6;       // 3200
    cpemb_w<<<blocksA, 256, 0, stream>>>(x, U0, U1, U2, w, ntok);

    // B: 4 waves/block, TPW tiles/wave
    const int nwaves  = (ngroups + TPW - 1) / TPW;   // 3200
    const int blocksB = (nwaves + 3) >> 2;           // 800
    cpemb_expand<<<blocksB, 256, 0, stream>>>(w, V0, V1, out, ntok);
}

// Round 9
// 26.938 us; speedup vs baseline: 1.5906x; 1.5906x over previous
//
#include <hip/hip_runtime.h>
#include <hip/hip_bf16.h>

// CP tensorized embedding gather via MFMA — r2 skeleton + gather prefetch:
// out[t, e] = sum_r w[t,r] * B[r,e]
//   w[t,r] = U0[a,r]*U1[b,r]*U2[c,r], idx=x[t], a=idx/5000, b=(idx/50)%100, c=idx%50
//   B[r,e] = V0[e>>4,r]*V1[e&15,r]
// Evidence r2..r8: store geometry (r7), occupancy (r6), kernel split (r8) all
// exonerated; the un-fixed defect in the best (27us) skeleton is front-end
// exposure: tile k+1's gathers were issued AFTER tile k's 32 stores, so their
// wait sat behind the store FIFO. Fix: hoist all x-loads; issue tile k+1's 6
// U-gathers BEFORE tile k's MFMA+stores (vmcnt retires in issue order, so the
// gather wait never waits on stores). No launch_bounds cap (r5's mistake).

#define RANKK 32
#define EMB 128

typedef __attribute__((ext_vector_type(8))) short short8v;  // 8 bf16 = 4 VGPRs
typedef __attribute__((ext_vector_type(4))) float f32x4;

__device__ __forceinline__ short f2bf(float f) {
    union { __hip_bfloat16 h; short s; } u;
    u.h = __float2bfloat16(f);   // RNE
    return u.s;
}

struct G6 { float4 a0, a1, b0, b1, c0, c1; };

__device__ __forceinline__ G6 gather6(unsigned ui,
    const float* __restrict__ U0, const float* __restrict__ U1,
    const float* __restrict__ U2, int rb)
{
    const unsigned a   = ui / 5000u;
    const unsigned rem = ui - a * 5000u;
    const unsigned b   = rem / 50u;
    const unsigned c   = rem - b * 50u;
    const float4* p0 = (const float4*)(U0 + a * RANKK + rb);
    const float4* p1 = (const float4*)(U1 + b * RANKK + rb);
    const float4* p2 = (const float4*)(U2 + c * RANKK + rb);
    G6 r;
    r.a0 = p0[0]; r.a1 = p0[1];
    r.b0 = p1[0]; r.b1 = p1[1];
    r.c0 = p2[0]; r.c1 = p2[1];
    return r;
}

__device__ __forceinline__ short8v mkafrag(const G6& q) {
    float wv[8];
    wv[0]=q.a0.x*q.b0.x*q.c0.x; wv[1]=q.a0.y*q.b0.y*q.c0.y;
    wv[2]=q.a0.z*q.b0.z*q.c0.z; wv[3]=q.a0.w*q.b0.w*q.c0.w;
    wv[4]=q.a1.x*q.b1.x*q.c1.x; wv[5]=q.a1.y*q.b1.y*q.c1.y;
    wv[6]=q.a1.z*q.b1.z*q.c1.z; wv[7]=q.a1.w*q.b1.w*q.c1.w;
    short8v af;
    #pragma unroll
    for (int i = 0; i < 8; ++i) af[i] = f2bf(wv[i]);
    return af;
}

__global__ __launch_bounds__(256) void cpemb_mfma(
    const int* __restrict__ x,
    const float* __restrict__ U0, const float* __restrict__ U1,
    const float* __restrict__ U2,
    const float* __restrict__ V0, const float* __restrict__ V1,
    float* __restrict__ out, int ntok)
{
    const int tid  = threadIdx.x;
    const int lane = tid & 63;
    const int gw   = blockIdx.x * 4 + (tid >> 6);
    const int nw   = gridDim.x * 4;
    const int ngroups = (ntok + 15) >> 4;   // 16-token tiles

    const int t_l = lane & 15;   // token-within-tile (A row / D col-partner)
    const int g   = lane >> 4;   // k-chunk group; D row block (g*4+j)
    const int rb  = g * 8;       // rank base (k = rb..rb+7)

    // ---- hoisted token-index loads for all (<=4) tiles of this wave ----
    unsigned ui[4];
    bool has[4];
    #pragma unroll
    for (int k = 0; k < 4; ++k) {
        int grp = gw + k * nw;
        has[k] = grp < ngroups;
        if (grp >= ngroups) grp = ngroups - 1;
        int tok = (grp << 4) + t_l;
        if (tok >= ntok) tok = ntok - 1;
        ui[k] = (unsigned)x[tok];
    }

    // ---- loop-invariant table fragments (MFMA B operand):
    // col e = eb*16 + t_l -> V1 row = t_l (fixed), V0 row = eb (uniform).
    float v1r[8];
    {
        const float4* p = (const float4*)(V1 + t_l * RANKK + rb);
        float4 lo = p[0], hi = p[1];
        v1r[0]=lo.x; v1r[1]=lo.y; v1r[2]=lo.z; v1r[3]=lo.w;
        v1r[4]=hi.x; v1r[5]=hi.y; v1r[6]=hi.z; v1r[7]=hi.w;
    }
    short8v bfrag[8];
    #pragma unroll
    for (int eb = 0; eb < 8; ++eb) {
        const float4* p = (const float4*)(V0 + eb * RANKK + rb);
        float4 lo = p[0], hi = p[1];
        float v0r[8] = {lo.x, lo.y, lo.z, lo.w, hi.x, hi.y, hi.z, hi.w};
        #pragma unroll
        for (int i = 0; i < 8; ++i)
            bfrag[eb][i] = f2bf(v0r[i] * v1r[i]);
    }

    if (!has[0]) return;

    // ---- software pipeline: gathers for tile k+1 issued BEFORE tile k's
    // MFMA + stores, so their latency hides under compute/store issue and
    // their wait (in-order vmcnt) never waits on stores.
    G6 cg = gather6(ui[0], U0, U1, U2, rb);

    #pragma unroll
    for (int k = 0; k < 4; ++k) {
        if (!has[k]) break;

        const bool pn = (k + 1 < 4) && has[k + 1];
        G6 ng;
        if (pn) ng = gather6(ui[k + 1], U0, U1, U2, rb);

        short8v afrag = mkafrag(cg);   // waits only on cg's 6 loads

        // ---- 8 MFMAs + stores (r2's exact layout: row=token, col=e)
        const int grp = gw + k * nw;
        const int t0  = grp << 4;
        const bool ok = (t0 + t_l) < ntok;
        float* ob = out + (size_t)(t0 + g * 4) * EMB + t_l;
        #pragma unroll
        for (int eb = 0; eb < 8; ++eb) {
            f32x4 z = {0.f, 0.f, 0.f, 0.f};
            f32x4 acc = __builtin_amdgcn_mfma_f32_16x16x32_bf16(afrag, bfrag[eb], z, 0, 0, 0);
            if (ok) {
                #pragma unroll
                for (int j = 0; j < 4; ++j)
                    ob[(size_t)j * EMB + eb * 16] = acc[j];
            }
        }

        if (pn) cg = ng;
    }
}

extern "C" void kernel_launch(void* const* d_in, const int* in_sizes, int n_in,
                              void* d_out, int out_size, void* d_ws, size_t ws_size,
                              hipStream_t stream) {
    const int*   x  = (const int*)d_in[0];
    const float* U0 = (const float*)d_in[1];
    const float* U1 = (const float*)d_in[2];
    const float* U2 = (const float*)d_in[3];
    const float* V0 = (const float*)d_in[4];
    const float* V1 = (const float*)d_in[5];
    float* out = (float*)d_out;

    const int ntok = in_sizes[0];   // 204800 -> 12800 tiles, 3-4 per wave
    const int blocks = 1024;        // r2's known-best grid (4 blocks/CU)

    cpemb_mfma<<<blocks, 256, 0, stream>>>(x, U0, U1, U2, V0, V1, out, ntok);
}